// Round 9
// baseline (205.815 us; speedup 1.0000x reference)
//
#include <hip/hip_runtime.h>

#define NPTS 8192
#define NSLICE 32
#define SLICE_LEN (NPTS / NSLICE)
#define KNN 8

typedef short bf16x8 __attribute__((ext_vector_type(8)));
typedef float f32x4 __attribute__((ext_vector_type(4)));

// bf16 round-to-nearest-even split helpers.
__device__ __forceinline__ unsigned short f2bf(float x) {
  unsigned int u = __float_as_uint(x);
  return (unsigned short)((u + 0x7FFF + ((u >> 16) & 1)) >> 16);
}
__device__ __forceinline__ float bf2f(unsigned short s) {
  return __uint_as_float(((unsigned int)s) << 16);
}

// Exact distance, replicating numpy rounding. Same bits every use.
__device__ __forceinline__ float dist_exact(float qx, float qy, float qz,
                                            float q2, float px, float py,
                                            float pz, float p2) {
  float dot = __fmaf_rn(qz, pz, __fmaf_rn(qy, py, __fmul_rn(qx, px)));
  float t1 = __fadd_rn(q2, p2);
  return __fadd_rn(t1, __fmul_rn(-2.0f, dot));
}

__device__ __forceinline__ float norm2_exact(float x, float y, float z) {
  return __fadd_rn(__fadd_rn(__fmul_rn(x, x), __fmul_rn(y, y)),
                   __fmul_rn(z, z));
}

// Monotone (d, idx) -> f64 key (as R8, verified): lex (d_bits, idx) order
// == IEEE f64 order; ascending keys == jax.lax.top_k order.
__device__ __forceinline__ double pack_key(float d, int idx) {
  unsigned int ub = __float_as_uint(d);
  ub ^= (((unsigned int)((int)ub >> 31)) | 0x80000000u);
  unsigned int lo = (ub << 13) | (unsigned int)idx;
  unsigned int hi = 0x3ff00000u | (ub >> 19);
  return __hiloint2double((int)hi, (int)lo);
}

#define KEY_DECL                                                            \
  const double KINF = __longlong_as_double(0x7ff0000000000000LL);           \
  double k0 = KINF, k1 = KINF, k2 = KINF, k3 = KINF, k4 = KINF, k5 = KINF,  \
         k6 = KINF, k7 = KINF;

// Parallel sorted-insert using the med3 identity on a sorted array:
// k0' = min(x,k0); k_{s+1}' = min(max(x,k_s), k_{s+1}).
// 15 f64 ops, dependency depth 2 (vs 16-op carry chain) -> hides f64
// half-rate latency at moderate occupancy. All reads from OLD values.
#define KEY_INSERT(key)                                                     \
  {                                                                         \
    double x = (key);                                                       \
    double m0 = fmax(x, k0), m1 = fmax(x, k1), m2 = fmax(x, k2);            \
    double m3 = fmax(x, k3), m4 = fmax(x, k4), m5 = fmax(x, k5);            \
    double m6 = fmax(x, k6);                                                \
    k7 = fmin(m6, k7);                                                      \
    k6 = fmin(m5, k6);                                                      \
    k5 = fmin(m4, k5);                                                      \
    k4 = fmin(m3, k4);                                                      \
    k3 = fmin(m2, k3);                                                      \
    k2 = fmin(m1, k2);                                                      \
    k1 = fmin(m0, k1);                                                      \
    k0 = fmin(x, k0);                                                       \
  }

// ---------------------------------------------------------------------------
// KNN phase 1: per (query, slice of 256) keep top-8 (d,idx) as f64 keys.
// grid dim3(32, 32) = 1024 blocks -> 4 blocks/CU -> 16 waves/CU TLP.
// Output: part_k[q*256 + slice*8 + s] (per-query contiguous).
// ---------------------------------------------------------------------------
__global__ __launch_bounds__(256) void knn_pairs_kernel(
    const float* __restrict__ pts, double* __restrict__ part_k) {
  __shared__ float4 sp[SLICE_LEN];
  const int t = threadIdx.x;
  const int q = blockIdx.x * 256 + t;
  const int jbase = blockIdx.y * SLICE_LEN;
  if (t < SLICE_LEN) {
    float x = pts[(jbase + t) * 3 + 0];
    float y = pts[(jbase + t) * 3 + 1];
    float z = pts[(jbase + t) * 3 + 2];
    sp[t] = make_float4(x, y, z, norm2_exact(x, y, z));
  }
  __syncthreads();
  const float qx = pts[q * 3 + 0], qy = pts[q * 3 + 1], qz = pts[q * 3 + 2];
  const float q2 = norm2_exact(qx, qy, qz);
  KEY_DECL;
  for (int p = 0; p < SLICE_LEN; p += 4) {
    float4 c0 = sp[p + 0];
    float4 c1 = sp[p + 1];
    float4 c2 = sp[p + 2];
    float4 c3 = sp[p + 3];
    {
      float d = dist_exact(qx, qy, qz, q2, c0.x, c0.y, c0.z, c0.w);
      KEY_INSERT(pack_key(d, jbase + p + 0));
    }
    {
      float d = dist_exact(qx, qy, qz, q2, c1.x, c1.y, c1.z, c1.w);
      KEY_INSERT(pack_key(d, jbase + p + 1));
    }
    {
      float d = dist_exact(qx, qy, qz, q2, c2.x, c2.y, c2.z, c2.w);
      KEY_INSERT(pack_key(d, jbase + p + 2));
    }
    {
      float d = dist_exact(qx, qy, qz, q2, c3.x, c3.y, c3.z, c3.w);
      KEY_INSERT(pack_key(d, jbase + p + 3));
    }
  }
  double* o = &part_k[(size_t)q * (NSLICE * KNN) + blockIdx.y * 8];
  o[0] = k0; o[1] = k1; o[2] = k2; o[3] = k3;
  o[4] = k4; o[5] = k5; o[6] = k6; o[7] = k7;
}

// ---------------------------------------------------------------------------
// KNN phase 2: merge 256 keys/query -> nbr. grid 128 x 64 (more CUs busy).
// ---------------------------------------------------------------------------
__global__ __launch_bounds__(64) void knn_merge2_kernel(
    const double* __restrict__ part_k, int* __restrict__ nbr) {
  const int q = blockIdx.x * 64 + threadIdx.x;
  const double* kv = &part_k[(size_t)q * (NSLICE * KNN)];
  KEY_DECL;
#pragma unroll 8
  for (int u = 0; u < NSLICE * KNN; u += 4) {
    double a = kv[u + 0];
    double b = kv[u + 1];
    double c = kv[u + 2];
    double d = kv[u + 3];
    KEY_INSERT(a);
    KEY_INSERT(b);
    KEY_INSERT(c);
    KEY_INSERT(d);
  }
  nbr[q * KNN + 0] = __double2loint(k0) & 0x1fff;
  nbr[q * KNN + 1] = __double2loint(k1) & 0x1fff;
  nbr[q * KNN + 2] = __double2loint(k2) & 0x1fff;
  nbr[q * KNN + 3] = __double2loint(k3) & 0x1fff;
  nbr[q * KNN + 4] = __double2loint(k4) & 0x1fff;
  nbr[q * KNN + 5] = __double2loint(k5) & 0x1fff;
  nbr[q * KNN + 6] = __double2loint(k6) & 0x1fff;
  nbr[q * KNN + 7] = __double2loint(k7) & 0x1fff;
}

// ---------------------------------------------------------------------------
// Fused EdgeConv1: H1 tile in LDS, GEMM W2, max8, +b2, relu -> y (8192x128).
// ---------------------------------------------------------------------------
__global__ __launch_bounds__(256) void gemm1_fused_kernel(
    const float* __restrict__ pts, const int* __restrict__ nbr,
    const float* __restrict__ W1, const float* __restrict__ b1,
    const float* __restrict__ W2, const float* __restrict__ b2,
    float* __restrict__ y) {
  __shared__ float es[64][6];
  __shared__ float W1s[6][64];
  __shared__ float b1s[64];
  __shared__ float As[64][64];
  __shared__ float Bs[64][64];
  const int t = threadIdx.x;
  const int rowBase = blockIdx.y * 64;
  const int colBase = blockIdx.x * 64;

  for (int idx = t; idx < 384; idx += 256) W1s[idx >> 6][idx & 63] = W1[idx];
  if (t < 64) b1s[t] = b1[t];
  {
    int cq = t & 15, kr = t >> 4;
#pragma unroll
    for (int it = 0; it < 4; ++it) {
      int k = it * 16 + kr;
      *(float4*)&Bs[k][cq * 4] =
          *(const float4*)&W2[(size_t)k * 128 + colBase + cq * 4];
    }
  }
  if (t < 64) {
    int e = rowBase + t;
    int i = e >> 3;
    int j = nbr[e];
    float xi0 = pts[i * 3], xi1 = pts[i * 3 + 1], xi2 = pts[i * 3 + 2];
    es[t][0] = xi0;
    es[t][1] = xi1;
    es[t][2] = xi2;
    es[t][3] = pts[j * 3] - xi0;
    es[t][4] = pts[j * 3 + 1] - xi1;
    es[t][5] = pts[j * 3 + 2] - xi2;
  }
  __syncthreads();

  {
    const int e = t & 63, k0 = (t >> 6) * 16;
    const float f0 = es[e][0], f1 = es[e][1], f2 = es[e][2];
    const float f3 = es[e][3], f4 = es[e][4], f5 = es[e][5];
#pragma unroll
    for (int k = 0; k < 16; ++k) {
      int c = k0 + k;
      float v = b1s[c];
      v = fmaf(f0, W1s[0][c], v);
      v = fmaf(f1, W1s[1][c], v);
      v = fmaf(f2, W1s[2][c], v);
      v = fmaf(f3, W1s[3][c], v);
      v = fmaf(f4, W1s[4][c], v);
      v = fmaf(f5, W1s[5][c], v);
      As[c][e] = fmaxf(v, 0.0f);
    }
  }
  __syncthreads();

  const int tx = t & 15, ty = t >> 4;
  float acc[4][4] = {};
#pragma unroll 8
  for (int k = 0; k < 64; ++k) {
    float4 a = *(const float4*)&As[k][ty * 4];
    float4 b = *(const float4*)&Bs[k][tx * 4];
    const float ar[4] = {a.x, a.y, a.z, a.w};
    const float br[4] = {b.x, b.y, b.z, b.w};
#pragma unroll
    for (int i = 0; i < 4; ++i)
#pragma unroll
      for (int jj = 0; jj < 4; ++jj)
        acc[i][jj] = fmaf(ar[i], br[jj], acc[i][jj]);
  }
  __syncthreads();

  float* Mx = &As[0][0];
#pragma unroll
  for (int jj = 0; jj < 4; ++jj) {
    float m =
        fmaxf(fmaxf(acc[0][jj], acc[1][jj]), fmaxf(acc[2][jj], acc[3][jj]));
    Mx[ty * 64 + tx * 4 + jj] = m;
  }
  __syncthreads();
  if (t < 128) {
    int p = t >> 4, cq = t & 15;
    int c = cq * 4;
    float4 o;
    float* oa = (float*)&o;
#pragma unroll
    for (int jj = 0; jj < 4; ++jj) {
      float v = fmaxf(Mx[(2 * p) * 64 + c + jj], Mx[(2 * p + 1) * 64 + c + jj]);
      v += b2[colBase + c + jj];
      oa[jj] = fmaxf(v, 0.0f);
    }
    *(float4*)&y[(size_t)(blockIdx.y * 8 + p) * 128 + colBase + c] = o;
  }
}

// Build Wcat (128 x 256) from W3 (256 x 128).
__global__ __launch_bounds__(256) void build_wcat_kernel(
    const float* __restrict__ W3, float* __restrict__ Wcat) {
  const int id = blockIdx.x * 256 + threadIdx.x;
  const int k = id >> 8, c = id & 255;
  Wcat[id] = (c < 128) ? W3[k * 128 + c] : W3[(128 + k) * 128 + (c - 128)];
}

// Split W4 (128x256 fp32) into transposed bf16 hi/lo: W4ht/W4lt[col*128+k].
__global__ __launch_bounds__(256) void w4split_kernel(
    const float* __restrict__ W4, unsigned short* __restrict__ W4ht,
    unsigned short* __restrict__ W4lt) {
  const int id = blockIdx.x * 256 + threadIdx.x;  // 32768
  const int k = id >> 8, c = id & 255;
  float v = W4[k * 256 + c];
  unsigned short hi = f2bf(v);
  unsigned short lo = f2bf(v - bf2f(hi));
  W4ht[c * 128 + k] = hi;
  W4lt[c * 128 + k] = lo;
}

// ---------------------------------------------------------------------------
// AC = y @ Wcat (+b3 on cols<128). 64x64 GEMM (8192x128x256).
// ---------------------------------------------------------------------------
__global__ __launch_bounds__(256) void gemm_ac_kernel(
    const float* __restrict__ A, const float* __restrict__ B,
    const float* __restrict__ bias, float* __restrict__ out) {
  __shared__ float As[64][64];
  __shared__ float Bs[64][64];
  const int t = threadIdx.x;
  const int tx = t & 15, ty = t >> 4;
  const int rowBase = blockIdx.y * 64;
  const int colBase = blockIdx.x * 64;
  const float4* A4 = (const float4*)A;
  float acc[4][4] = {};
  const int K = 128, Nglob = 256;

  for (int k0 = 0; k0 < K; k0 += 64) {
#pragma unroll
    for (int it = 0; it < 4; ++it) {
      int idx = it * 256 + t;
      int row = idx & 63, kq = idx >> 6;
      float4 av = A4[(size_t)(rowBase + row) * (K >> 2) + (k0 >> 2) + kq];
      As[kq * 4 + 0][row] = av.x;
      As[kq * 4 + 1][row] = av.y;
      As[kq * 4 + 2][row] = av.z;
      As[kq * 4 + 3][row] = av.w;
    }
#pragma unroll
    for (int it = 0; it < 4; ++it) {
      int idx = it * 256 + t;
      int cq = idx & 15, kr = idx >> 4;
      float4 bv =
          *(const float4*)&B[(size_t)(k0 + kr) * Nglob + colBase + cq * 4];
      *(float4*)&Bs[kr][cq * 4] = bv;
    }
    __syncthreads();
#pragma unroll 8
    for (int k = 0; k < 64; ++k) {
      float4 a = *(const float4*)&As[k][ty * 4];
      float4 b = *(const float4*)&Bs[k][tx * 4];
      const float ar[4] = {a.x, a.y, a.z, a.w};
      const float br[4] = {b.x, b.y, b.z, b.w};
#pragma unroll
      for (int i = 0; i < 4; ++i)
#pragma unroll
        for (int jj = 0; jj < 4; ++jj)
          acc[i][jj] = fmaf(ar[i], br[jj], acc[i][jj]);
    }
    __syncthreads();
  }

#pragma unroll
  for (int i = 0; i < 4; ++i) {
    float4 o;
    float* oa = (float*)&o;
#pragma unroll
    for (int jj = 0; jj < 4; ++jj) {
      float v = acc[i][jj];
      int cg = colBase + tx * 4 + jj;
      if (cg < 128) v += bias[cg];
      oa[jj] = v;
    }
    *(float4*)&out[(size_t)(rowBase + ty * 4 + i) * Nglob + colBase + tx * 4] =
        o;
  }
}

// ---------------------------------------------------------------------------
// MFMA EdgeConv2 second layer (split-bf16), as R7 (verified):
// D = Hh*Wh + Hh*Wl + Hl*Wh in fp32 MFMA acc; in-register segmax + b4.
// ---------------------------------------------------------------------------
__global__ __launch_bounds__(256) void gemm2_mfma_kernel(
    const float* __restrict__ AC, const int* __restrict__ nbr,
    const unsigned short* __restrict__ W4ht,
    const unsigned short* __restrict__ W4lt, const float* __restrict__ b4,
    float* __restrict__ out) {
  __shared__ unsigned short H2h[128 * 40];
  __shared__ unsigned short H2l[128 * 40];
  __shared__ unsigned short Wth[128 * 40];
  __shared__ unsigned short Wtl[128 * 40];
  const int t = threadIdx.x;
  const int rowBase = blockIdx.y * 128;
  const int colBase = blockIdx.x * 128;
  const int eloc = t >> 1, hh = t & 1;
  const int kb = hh * 16;
  const int edge = rowBase + eloc;
  const int ip = edge >> 3;
  const int jp = nbr[edge];
  const float* ai_p = AC + (size_t)ip * 256;
  const float* ci_p = ai_p + 128;
  const float* cj_p = AC + (size_t)jp * 256 + 128;
  const int lane = t & 63;
  const int w = t >> 6;
  const int q = lane >> 4;
  const int nidx = lane & 15;

  f32x4 acc[2][8];
#pragma unroll
  for (int mt = 0; mt < 2; ++mt)
#pragma unroll
    for (int nt = 0; nt < 8; ++nt) acc[mt][nt] = (f32x4){0.f, 0.f, 0.f, 0.f};

  for (int p = 0; p < 4; ++p) {
    const int k0 = p * 32;
    {
      float h2[16];
      const float4* a4 = (const float4*)(ai_p + k0 + kb);
      const float4* c4 = (const float4*)(ci_p + k0 + kb);
      const float4* d4 = (const float4*)(cj_p + k0 + kb);
#pragma unroll
      for (int u = 0; u < 4; ++u) {
        float4 a = a4[u], c = c4[u], d = d4[u];
        h2[u * 4 + 0] = fmaxf(a.x + d.x - c.x, 0.f);
        h2[u * 4 + 1] = fmaxf(a.y + d.y - c.y, 0.f);
        h2[u * 4 + 2] = fmaxf(a.z + d.z - c.z, 0.f);
        h2[u * 4 + 3] = fmaxf(a.w + d.w - c.w, 0.f);
      }
      unsigned int hp[8], lp[8];
#pragma unroll
      for (int u = 0; u < 8; ++u) {
        unsigned short h0 = f2bf(h2[2 * u]), h1 = f2bf(h2[2 * u + 1]);
        hp[u] = (unsigned int)h0 | ((unsigned int)h1 << 16);
        unsigned short l0 = f2bf(h2[2 * u] - bf2f(h0));
        unsigned short l1 = f2bf(h2[2 * u + 1] - bf2f(h1));
        lp[u] = (unsigned int)l0 | ((unsigned int)l1 << 16);
      }
      *(uint4*)&H2h[eloc * 40 + kb] = make_uint4(hp[0], hp[1], hp[2], hp[3]);
      *(uint4*)&H2h[eloc * 40 + kb + 8] =
          make_uint4(hp[4], hp[5], hp[6], hp[7]);
      *(uint4*)&H2l[eloc * 40 + kb] = make_uint4(lp[0], lp[1], lp[2], lp[3]);
      *(uint4*)&H2l[eloc * 40 + kb + 8] =
          make_uint4(lp[4], lp[5], lp[6], lp[7]);
    }
    {
      const size_t src = (size_t)(colBase + eloc) * 128 + k0 + kb;
      *(uint4*)&Wth[eloc * 40 + kb] = *(const uint4*)&W4ht[src];
      *(uint4*)&Wth[eloc * 40 + kb + 8] = *(const uint4*)&W4ht[src + 8];
      *(uint4*)&Wtl[eloc * 40 + kb] = *(const uint4*)&W4lt[src];
      *(uint4*)&Wtl[eloc * 40 + kb + 8] = *(const uint4*)&W4lt[src + 8];
    }
    __syncthreads();
    bf16x8 ah[2], al[2];
#pragma unroll
    for (int mt = 0; mt < 2; ++mt) {
      int row = w * 32 + mt * 16 + nidx;
      ah[mt] = *(const bf16x8*)&H2h[row * 40 + q * 8];
      al[mt] = *(const bf16x8*)&H2l[row * 40 + q * 8];
    }
#pragma unroll
    for (int nt = 0; nt < 8; ++nt) {
      int col = nt * 16 + nidx;
      bf16x8 bh = *(const bf16x8*)&Wth[col * 40 + q * 8];
      bf16x8 bl = *(const bf16x8*)&Wtl[col * 40 + q * 8];
#pragma unroll
      for (int mt = 0; mt < 2; ++mt) {
        acc[mt][nt] = __builtin_amdgcn_mfma_f32_16x16x32_bf16(
            ah[mt], bh, acc[mt][nt], 0, 0, 0);
        acc[mt][nt] = __builtin_amdgcn_mfma_f32_16x16x32_bf16(
            ah[mt], bl, acc[mt][nt], 0, 0, 0);
        acc[mt][nt] = __builtin_amdgcn_mfma_f32_16x16x32_bf16(
            al[mt], bh, acc[mt][nt], 0, 0, 0);
      }
    }
    __syncthreads();
  }

#pragma unroll
  for (int mt = 0; mt < 2; ++mt) {
    const int ebase = rowBase + w * 32 + mt * 16;
    const int pt0 = ebase >> 3;
#pragma unroll
    for (int nt = 0; nt < 8; ++nt) {
      f32x4 a = acc[mt][nt];
      float m = fmaxf(fmaxf(a[0], a[1]), fmaxf(a[2], a[3]));
      float o = fmaxf(m, __shfl_xor(m, 16, 64));
      int cg = colBase + nt * 16 + nidx;
      if (q == 0) {
        out[(size_t)pt0 * 256 + cg] = o + b4[cg];
      } else if (q == 2) {
        out[(size_t)(pt0 + 1) * 256 + cg] = o + b4[cg];
      }
    }
  }
}

extern "C" void kernel_launch(void* const* d_in, const int* in_sizes, int n_in,
                              void* d_out, int out_size, void* d_ws,
                              size_t ws_size, hipStream_t stream) {
  const float* pts = (const float*)d_in[0];
  const float* W1 = (const float*)d_in[1];
  const float* b1 = (const float*)d_in[2];
  const float* W2 = (const float*)d_in[3];
  const float* b2 = (const float*)d_in[4];
  const float* W3 = (const float*)d_in[5];
  const float* b3 = (const float*)d_in[6];
  const float* W4 = (const float*)d_in[7];
  const float* b4 = (const float*)d_in[8];
  float* out = (float*)d_out;

  float* w = (float*)d_ws;
  double* part_k = (double*)w;                 // 8192*256 dbl = 4194304 f
  int* nbr = (int*)(w + 4194304);              // 65536 i
  float* y = w + 4259840;                      // 1048576 f
  float* Wcat = w + 5308416;                   // 32768 f
  float* AC = w + 5341184;                     // 2097152 f
  unsigned short* W4ht = (unsigned short*)(w + 7438336);  // 32768 us
  unsigned short* W4lt = (unsigned short*)(w + 7454720);  // 32768 us

  // 1. KNN: keyed (d,idx) f64 top-8 per slice (32 slices) -> merge -> nbr
  knn_pairs_kernel<<<dim3(32, NSLICE), 256, 0, stream>>>(pts, part_k);
  knn_merge2_kernel<<<128, 64, 0, stream>>>(part_k, nbr);

  // 2. EdgeConv1 (fused H1 + GEMM + max8 + b2 + relu)
  gemm1_fused_kernel<<<dim3(2, 1024), 256, 0, stream>>>(pts, nbr, W1, b1, W2,
                                                        b2, y);

  // 3. EdgeConv2: AC = y@Wcat (+b3), then MFMA H2+GEMM+max8+b4 -> out
  build_wcat_kernel<<<128, 256, 0, stream>>>(W3, Wcat);
  w4split_kernel<<<128, 256, 0, stream>>>(W4, W4ht, W4lt);
  gemm_ac_kernel<<<dim3(4, 128), 256, 0, stream>>>(y, Wcat, b3, AC);
  gemm2_mfma_kernel<<<dim3(2, 512), 256, 0, stream>>>(AC, nbr, W4ht, W4lt, b4,
                                                      out);
}